// Round 13
// baseline (310.975 us; speedup 1.0000x reference)
//
#include <hip/hip_runtime.h>

// KNN argmin over L2, round 32: exact R25 base (prep + LDS phaseA, best
// 145.8us) + phaseB restructured 4-wave/4096-WG -> 2-wave/8192-WG.
//
// R31 post-mortem: forced 64-wide staging engaged (VGPR 56->108) and
// REGRESSED (48.7->67.5, occ 18.8%): per-item-latency axis dead; R21's
// compiler 12-wide staging is optimal. phaseA _ord0=139us @ occ 1.9% =
// first-iteration warmup artifact (steady-state unchanged).
//
// Rounds-x-chain model (fits all phaseB points): dur ~= sched_rounds x
// per-WG serial chain (~9us: Q load -> bmin -> threshold -> ~5 stolen
// items -> merges). R21: 5.3 rounds -> 48.7. R31: 8 rounds -> 67.5
// (x1.5 rounds, x1.39 dur). R29: 8 serial iters -> 65. R20: rounds down
// but chain up (VGPR 28) -> flat. Untried corner: MORE, SMALLER WGs.
// R32 phaseB: 128 thr (2 waves), 8192 WGs, 2 queries/WG. Chain ~halves,
// rounds 5.3 -> ~2.7 (launch_bounds(128,6): VGPR cap ~85 >> 56 used, ~12
// blocks/CU). Stealing/merge logic identical with 2 waves; same
// first-index proof (ascending block order per query, strict-<, lex
// merges with index tiebreak). R21 staging body verbatim.
//
// Certificate unchanged: c=2^-9*1.01<=0.002, eps=0.004|q|^2+0.05; bmin
// encodes 0.998|s|^2 - 2*cross_f16 via cinit=-0.499|s|^2 (sqSc).
// Rescoring all blocks with bmin <= min+eps provably contains the true
// first argmin. absmax must stay 0.
//
// Ledger: R19 153.3 | R20 153.0 | R21 145.8 | R22 no-op | R23 314.8
// spills | R24 153.1 | R25 145.8 BEST | R26 221.7 | R27 203.9 | R28
// 160.7 | R29 166.1 | R30 197.7 | R31 168.3 (wide staging dead).
// Prediction: phaseB 24-34us @ occ 40-55; total ~120-132. Falsifier:
// phaseB >=45 kills rounds-x-chain -> revert to R25 and conclude.

#define NTOT   16384
#define DIM    64
#define EPS_COEF 0.004f   // 2c with c=0.002 (>= 2^-9*1.01)
#define EPS_ABS  0.05f
#define CINIT_COEF (-0.499f)  // -(1-c)/2
#define FLT_BIG 3.4e38f

typedef __attribute__((ext_vector_type(8))) short short8;
typedef __attribute__((ext_vector_type(4))) float float4v;

__device__ __forceinline__ ushort f16_bits(float x) {
  union { _Float16 f; ushort u; } c;
  c.f = (_Float16)x;  // v_cvt_f16_f32, RNE
  return c.u;
}

// Opaque def: forbids rematerialization (forces register residency).
__device__ __forceinline__ void pin8(short8& v) {
  asm volatile("" : "+v"(v));
}

#define MFMA16F(A, B, C) __builtin_amdgcn_mfma_f32_16x16x32_f16(A, B, C, 0, 0, 0)

// ---------------------------------------------------------------------------
// Fused prep (R22/R25 verbatim): blocks 0..255 -> S (f16 panels + sqS +
// sqSc + S_T); 256..511 -> Q (panels + sqQ). Panel layout (R8-proven):
//   off(r,k) = (r>>4)*1024 + (k>>5)*512 + (((k&31)>>3)*16 + (r&15))*8 + (k&7)
__global__ __launch_bounds__(256) void k_prep(
    const float* __restrict__ S, const float* __restrict__ Q,
    ushort* __restrict__ Sh, ushort* __restrict__ Qh,
    float* __restrict__ sqS, float* __restrict__ sqQ,
    float* __restrict__ sqSc, float* __restrict__ S_T) {
  __shared__ float tile[64][65];
  const int tid = threadIdx.x;
  const bool isS = blockIdx.x < 256;
  const int rbase = (blockIdx.x & 255) * 64;
  const float* __restrict__ src = isS ? S : Q;
  ushort* __restrict__ dh = isS ? Sh : Qh;

  const int tx = tid & 63;
  const int ty = tid >> 6;
#pragma unroll
  for (int i = 0; i < 16; ++i) {
    const int r = i * 4 + ty;
    tile[r][tx] = src[(size_t)(rbase + r) * DIM + tx];  // coalesced
  }
  __syncthreads();

  if (isS) {  // transposed copy (coalesced, pad-safe)
#pragma unroll
    for (int i = 0; i < 16; ++i) {
      const int d = i * 4 + ty;
      S_T[(size_t)d * NTOT + rbase + tx] = tile[tx][d];
    }
  }

  // Panel-swizzled f16; stores are lane-contiguous 16B.
  const int panel = tid >> 6;           // 0..3
  const int half = (tid >> 5) & 1;      // k-half
  const int slot0 = (tid & 31) * 2;     // slot = q8*16 + m
#pragma unroll
  for (int ss = 0; ss < 2; ++ss) {
    const int s = slot0 + ss;
    const int m = s & 15;
    const int q8 = s >> 4;
    const int row = panel * 16 + m;
    const int kb = half * 32 + q8 * 8;
    short8 hv;
#pragma unroll
    for (int j = 0; j < 8; ++j) hv[j] = (short)f16_bits(tile[row][kb + j]);
    const size_t goff =
        (size_t)((rbase >> 4) + panel) * 1024 + (size_t)half * 512 + (size_t)s * 8;
    *(short8*)&dh[goff] = hv;
  }

  // Row sum of squares (+ pre-scaled C-init for phaseA on the S side).
  if (tid < 64) {
    float acc = 0.0f;
#pragma unroll
    for (int d = 0; d < DIM; ++d) {
      const float v = tile[tid][d];
      acc = fmaf(v, v, acc);
    }
    if (isS) {
      sqS[rbase + tid] = acc;
      sqSc[rbase + tid] = CINIT_COEF * acc;  // same v_mul RNE as before
    } else {
      sqQ[rbase + tid] = acc;
    }
  }
}

// ---------------------------------------------------------------------------
// Phase A (R25 verbatim): block = 256 queries x 512 supports; 4 waves
// share the support panel via LDS (double-buffered 64-support chunks,
// global_load_lds width=16, linear dest, R8 lane-contiguous layout).
// grid = (32 splits, 64 q-tiles); split -> XCD via linear%8.
template <int BST>  // 16-support steps per bmin block: 8 -> SBLK=128
__global__ __launch_bounds__(256, 4) void k_phaseA(
    const ushort* __restrict__ Sh, const ushort* __restrict__ Qh,
    const float* __restrict__ sqSc, float* __restrict__ bmin) {
  constexpr int NSB = NTOT / (16 * BST);   // 128 or 64
  constexpr int SBLK = 16 * BST;
  __shared__ ushort spanel[2][4096];       // 2 x 8KB: 64 supports each
  __shared__ float ssq[2][64];

  const int tid = threadIdx.x;
  const int l = tid & 63;
  const int w = tid >> 6;
  const int lm = l & 15;
  const int lq = l >> 4;
  const int split = blockIdx.x;            // 0..31
  const int qbase = blockIdx.y * 256 + w * 64;
  const int sbase = split * 512;

  // Query (B) fragments: 4 tiles x 2 k-chunks, pinned (32 VGPR resident).
  short8 qh[4][2];
#pragma unroll
  for (int t = 0; t < 4; ++t) {
    const size_t pb = (size_t)((qbase >> 4) + t) * 1024 + (size_t)l * 8;
    qh[t][0] = *(const short8*)&Qh[pb];
    qh[t][1] = *(const short8*)&Qh[pb + 512];
  }
#pragma unroll
  for (int t = 0; t < 4; ++t) {
    pin8(qh[t][0]);
    pin8(qh[t][1]);
  }

  // Async stage of chunk c into buffer b; LDS dest is linear
  // (wave-uniform base + lane*16), panel layout is lane-contiguous.
  auto stage = [&](int c, int b) {
    const ushort* gs = Sh + ((size_t)(split * 32 + c * 4)) * 1024 +
                       (size_t)w * 1024 + (size_t)l * 8;
    ushort* ls = &spanel[b][w * 1024];
    __builtin_amdgcn_global_load_lds(
        (const __attribute__((address_space(1))) void*)(const void*)gs,
        (__attribute__((address_space(3))) void*)(void*)ls, 16, 0, 0);
    __builtin_amdgcn_global_load_lds(
        (const __attribute__((address_space(1))) void*)(const void*)(gs + 512),
        (__attribute__((address_space(3))) void*)(void*)(ls + 512), 16, 0, 0);
    if (tid < 16)
      *(float4*)&ssq[b][tid * 4] =
          *(const float4*)&sqSc[sbase + c * 64 + tid * 4];
  };

  float bmr[4] = {-FLT_BIG, -FLT_BIG, -FLT_BIG, -FLT_BIG};

  stage(0, 0);
  __syncthreads();  // implicit vmcnt(0) drain: chunk 0 resident

  for (int c = 0; c < 8; ++c) {
    const int b = c & 1;
    if (c + 1 < 8) stage(c + 1, b ^ 1);  // async issue before compute

#pragma unroll
    for (int st = 0; st < 4; ++st) {
      const short8 h0 = *(const short8*)&spanel[b][st * 1024 + l * 8];
      const short8 h1 = *(const short8*)&spanel[b][st * 1024 + 512 + l * 8];
      const float4 sqv = *(const float4*)&ssq[b][st * 16 + lq * 4];
      float4v cinit;
      cinit[0] = sqv.x;
      cinit[1] = sqv.y;
      cinit[2] = sqv.z;
      cinit[3] = sqv.w;
#pragma unroll
      for (int t = 0; t < 4; ++t) {
        float4v a = MFMA16F(h0, qh[t][0], cinit);
        a = MFMA16F(h1, qh[t][1], a);
        // v_max3(a0,a1,a2) + max(a3,bmr) + max. Exact (assoc/comm).
        bmr[t] = fmaxf(fmaxf(fmaxf(a[0], a[1]), a[2]), fmaxf(a[3], bmr[t]));
      }
    }

    if ((((c + 1) * 4) & (BST - 1)) == 0) {  // finished a bmin block
      const int gb = split * (512 / SBLK) + ((c + 1) * 64 / SBLK) - 1;
#pragma unroll
      for (int t = 0; t < 4; ++t) {
        float v = bmr[t];
        v = fmaxf(v, __shfl_xor(v, 16, 64));
        v = fmaxf(v, __shfl_xor(v, 32, 64));
        if (lq == 0) bmin[(size_t)(qbase + t * 16 + lm) * NSB + gb] = -2.0f * v;
        bmr[t] = -FLT_BIG;
      }
    }
    __syncthreads();  // drains stage(c+1) + guards buffer reuse
  }
}

// ---------------------------------------------------------------------------
// Phase B (R32): 128 threads = 2 waves, 2 queries per block, 8192 blocks.
// Wave w owns query blockIdx*2+w; the 2 waves publish passing-block masks
// to LDS and round-robin the combined worklist (alternate items). R21
// register-staged rescore verbatim. Exact fp32 keys, d-ascending
// accumulation; strict-< ascending per lane + lexicographic merges =>
// np.argmin first-index.
template <int SBLK>
__global__ __launch_bounds__(128, 6) void k_phaseB(
    const float* __restrict__ S_T,   // [64][NTOT]
    const float* __restrict__ Q,     // [NTOT][64]
    const float* __restrict__ sqS, const float* __restrict__ sqQ,
    const float* __restrict__ bmin,
    const float* __restrict__ onehot, float* __restrict__ out) {
  constexpr int NSB = NTOT / SBLK;    // 128 or 64
  constexpr int NB64 = NSB / 64;
  constexpr int SPL = SBLK / 64;      // supports per lane: 2 or 4

  __shared__ float sQrow[2][64];
  __shared__ unsigned long long smask[2][NB64];
  __shared__ float sbk[2][2];
  __shared__ int sbi[2][2];

  const int lane = threadIdx.x & 63;
  const int w = threadIdx.x >> 6;     // 0..1
  const int q = blockIdx.x * 2 + w;

  if (lane < 16)
    *(float4*)&sQrow[w][lane * 4] = *(const float4*)&Q[(size_t)q * DIM + lane * 4];

  // Per-query certified filter width.
  const float eps = EPS_COEF * sqQ[q] + EPS_ABS;

  float bv[NB64];
#pragma unroll
  for (int j = 0; j < NB64; ++j) bv[j] = bmin[(size_t)q * NSB + j * 64 + lane];
  float m = bv[0];
#pragma unroll
  for (int j = 1; j < NB64; ++j) m = fminf(m, bv[j]);
#pragma unroll
  for (int d = 1; d < 64; d <<= 1) m = fminf(m, __shfl_xor(m, d, 64));
  const float thr = m + eps;

#pragma unroll
  for (int j = 0; j < NB64; ++j) {
    const unsigned long long msk = __ballot(bv[j] <= thr);
    if (lane == 0) smask[w][j] = msk;
  }
  __syncthreads();  // sQrow + smask visible block-wide

  // Round-robin the combined worklist (ascending block order per query
  // => per-lane ascending support index => strict-< keeps FIRST min).
  int idx = 0;
  for (int qq = 0; qq < 2; ++qq) {
    float bkq = FLT_BIG;
    int biq = 0;
    for (int j = 0; j < NB64; ++j) {
      unsigned long long msk = smask[qq][j];  // uniform broadcast read
      while (msk) {  // wave-uniform control
        const int b = j * 64 + (__ffsll((long long)msk) - 1);
        msk &= msk - 1;
        if ((idx++ & 1) != w) continue;
        const int s0 = b * SBLK + lane * SPL;
        if (SPL == 2) {
          // R21 register-staged rescore verbatim:
          // 2 halves x {32 float2 loads -> 64 fmaf}, d-ascending.
          float a0 = 0.f, a1 = 0.f;
#pragma unroll
          for (int h = 0; h < 2; ++h) {
            float2 x[32];
#pragma unroll
            for (int d = 0; d < 32; ++d)
              x[d] = *(const float2*)&S_T[(size_t)(h * 32 + d) * NTOT + s0];
#pragma unroll
            for (int d = 0; d < 32; ++d) {
              const float qd = sQrow[qq][h * 32 + d];
              a0 = fmaf(qd, x[d].x, a0);
              a1 = fmaf(qd, x[d].y, a1);
            }
          }
          const float2 sq2 = *(const float2*)&sqS[s0];
          const float k0 = fmaf(-2.f, a0, sq2.x);
          const float k1 = fmaf(-2.f, a1, sq2.y);
          bool u;  // ascending index, strict < => first minimum per lane
          u = k0 < bkq; bkq = u ? k0 : bkq; biq = u ? s0 : biq;
          u = k1 < bkq; bkq = u ? k1 : bkq; biq = u ? (s0 + 1) : biq;
        } else {
          // R21 SPL==4 path verbatim (fallback config).
          float a0 = 0.f, a1 = 0.f, a2 = 0.f, a3 = 0.f;
#pragma unroll
          for (int hh = 0; hh < 4; ++hh) {
            float4 x4[16];
#pragma unroll
            for (int d = 0; d < 16; ++d)
              x4[d] = *(const float4*)&S_T[(size_t)(hh * 16 + d) * NTOT + s0];
#pragma unroll
            for (int d = 0; d < 16; ++d) {
              const float qd = sQrow[qq][hh * 16 + d];
              a0 = fmaf(qd, x4[d].x, a0);
              a1 = fmaf(qd, x4[d].y, a1);
              a2 = fmaf(qd, x4[d].z, a2);
              a3 = fmaf(qd, x4[d].w, a3);
            }
          }
          const float4 sq4 = *(const float4*)&sqS[s0];
          const float k0 = fmaf(-2.f, a0, sq4.x);
          const float k1 = fmaf(-2.f, a1, sq4.y);
          const float k2 = fmaf(-2.f, a2, sq4.z);
          const float k3 = fmaf(-2.f, a3, sq4.w);
          bool u;
          u = k0 < bkq; bkq = u ? k0 : bkq; biq = u ? s0 : biq;
          u = k1 < bkq; bkq = u ? k1 : bkq; biq = u ? (s0 + 1) : biq;
          u = k2 < bkq; bkq = u ? k2 : bkq; biq = u ? (s0 + 2) : biq;
          u = k3 < bkq; bkq = u ? k3 : bkq; biq = u ? (s0 + 3) : biq;
        }
      }
    }
    // Cross-lane lexicographic argmin on exact keys => first-index.
#pragma unroll
    for (int d = 1; d < 64; d <<= 1) {
      const float ok = __shfl_xor(bkq, d, 64);
      const int oi = __shfl_xor(biq, d, 64);
      const bool u = (ok < bkq) || (ok == bkq && oi < biq);
      bkq = u ? ok : bkq;
      biq = u ? oi : biq;
    }
    if (lane == 0) { sbk[qq][w] = bkq; sbi[qq][w] = biq; }
  }
  __syncthreads();

  // Wave w: lexicographic merge of the 2 wave partials for query w.
  // (Disjoint item subsets; ties resolved by smaller index => first-index.)
  float fk = sbk[w][0];
  int fi = sbi[w][0];
  {
    const float ok = sbk[w][1];
    const int oi = sbi[w][1];
    const bool u = (ok < fk) || (ok == fk && oi < fi);
    fk = u ? ok : fk;
    fi = u ? oi : fi;
  }

  // Label: one-hot rows exact {0,1}; first 1 == np.argmax.
  const float ov = onehot[(size_t)fi * 64 + lane];
  const unsigned long long lmask = __ballot(ov > 0.5f);
  const int label = __ffsll((long long)lmask) - 1;
  out[(size_t)q * 64 + lane] = (lane == label) ? 1.0f : 0.0f;
}

// ---------------------------------------------------------------------------
extern "C" void kernel_launch(void* const* d_in, const int* in_sizes, int n_in,
                              void* d_out, int out_size, void* d_ws, size_t ws_size,
                              hipStream_t stream) {
  const float* S = (const float*)d_in[0];   // [16384][64]
  const float* Q = (const float*)d_in[1];   // [16384][64]
  const float* OH = (const float*)d_in[2];  // [16384][64]
  float* out = (float*)d_out;

  char* ws = (char*)d_ws;
  ushort* Sh = (ushort*)ws;                                  // [0, 2MB)
  ushort* Qh = (ushort*)(ws + (2u << 20));                   // [2, 4MB)
  float* S_T = (float*)(ws + (4u << 20));                    // [4, 8MB)
  float* sqS = (float*)(ws + (8u << 20));                    // 64 KB
  float* sqQ = (float*)(ws + (8u << 20) + (64u << 10));      // 64 KB
  float* sqSc = (float*)(ws + (8u << 20) + (128u << 10));    // 64 KB
  float* bmin = (float*)(ws + (8u << 20) + (192u << 10));    // up to 8 MB

  k_prep<<<dim3(512), 256, 0, stream>>>(S, Q, Sh, Qh, sqS, sqQ, sqSc, S_T);

  // 128-granular bmin (8 MB) if workspace allows; else 256-granular (4 MB).
  if (ws_size >= (17u << 20)) {
    k_phaseA<8><<<dim3(32, NTOT / 256), 256, 0, stream>>>(Sh, Qh, sqSc, bmin);
    k_phaseB<128><<<dim3(NTOT / 2), 128, 0, stream>>>(S_T, Q, sqS, sqQ,
                                                      bmin, OH, out);
  } else {
    k_phaseA<16><<<dim3(32, NTOT / 256), 256, 0, stream>>>(Sh, Qh, sqSc, bmin);
    k_phaseB<256><<<dim3(NTOT / 2), 128, 0, stream>>>(S_T, Q, sqS, sqQ,
                                                      bmin, OH, out);
  }
  (void)in_sizes; (void)n_in; (void)out_size; (void)ws_size;
}

// Round 14
// 145.681 us; speedup vs baseline: 2.1346x; 2.1346x over previous
//
#include <hip/hip_runtime.h>

// KNN argmin over L2, round 33: R32 with ONE change — launch_bounds
// (128,6) -> (128,2). R32's phaseB was a scratch-spill catastrophe, not
// a model test: VGPR 40 (< the 56 the staging arrays need), WRITE 580MB
// + FETCH 379MB = spill write+readback (18K items x 64 lanes x 512B each
// way). Third spill incident (R23, R30, R32); cap now 256 VGPR so the
// x[32] staging arrays cannot spill.
//
// Pre-registered checks:
//  - Spill check: VGPR must be ~56-70, WRITE ~4MB. Spill again => axis
//    cursed, revert to R25 and conclude.
//  - Model check (rounds x chain): 8192 x 128-thr WGs at ~16 blocks/CU
//    => ~2 scheduling rounds of a halved chain; predict phaseB 22-34us.
//    phaseB ~49 => model dead, R25 is the plateau.
//
// Everything else identical to R32: prep + phaseA are the R25-proven
// bodies (145.8us build); phaseB is 2-wave/2-query work stealing with
// R21's register-staged rescore verbatim. Exact fp32 keys, d-ascending
// accumulation, strict-< ascending + lexicographic merges => np.argmin
// first-index. absmax must stay 0.
//
// Certificate unchanged: c=2^-9*1.01<=0.002, eps=0.004|q|^2+0.05; bmin
// encodes 0.998|s|^2 - 2*cross_f16 via cinit=-0.499|s|^2 (sqSc).
// Rescoring all blocks with bmin <= min+eps provably contains the true
// first argmin.
//
// Ledger: R19 153.3 | R20 153.0 | R21 145.8 | R22 no-op | R23 314.8
// spills | R24 153.1 | R25 145.8 BEST | R26 221.7 | R27 203.9 | R28
// 160.7 | R29 166.1 | R30 197.7 spills | R31 168.3 | R32 311.0 spills.

#define NTOT   16384
#define DIM    64
#define EPS_COEF 0.004f   // 2c with c=0.002 (>= 2^-9*1.01)
#define EPS_ABS  0.05f
#define CINIT_COEF (-0.499f)  // -(1-c)/2
#define FLT_BIG 3.4e38f

typedef __attribute__((ext_vector_type(8))) short short8;
typedef __attribute__((ext_vector_type(4))) float float4v;

__device__ __forceinline__ ushort f16_bits(float x) {
  union { _Float16 f; ushort u; } c;
  c.f = (_Float16)x;  // v_cvt_f16_f32, RNE
  return c.u;
}

// Opaque def: forbids rematerialization (forces register residency).
__device__ __forceinline__ void pin8(short8& v) {
  asm volatile("" : "+v"(v));
}

#define MFMA16F(A, B, C) __builtin_amdgcn_mfma_f32_16x16x32_f16(A, B, C, 0, 0, 0)

// ---------------------------------------------------------------------------
// Fused prep (R22/R25 verbatim): blocks 0..255 -> S (f16 panels + sqS +
// sqSc + S_T); 256..511 -> Q (panels + sqQ). Panel layout (R8-proven):
//   off(r,k) = (r>>4)*1024 + (k>>5)*512 + (((k&31)>>3)*16 + (r&15))*8 + (k&7)
__global__ __launch_bounds__(256) void k_prep(
    const float* __restrict__ S, const float* __restrict__ Q,
    ushort* __restrict__ Sh, ushort* __restrict__ Qh,
    float* __restrict__ sqS, float* __restrict__ sqQ,
    float* __restrict__ sqSc, float* __restrict__ S_T) {
  __shared__ float tile[64][65];
  const int tid = threadIdx.x;
  const bool isS = blockIdx.x < 256;
  const int rbase = (blockIdx.x & 255) * 64;
  const float* __restrict__ src = isS ? S : Q;
  ushort* __restrict__ dh = isS ? Sh : Qh;

  const int tx = tid & 63;
  const int ty = tid >> 6;
#pragma unroll
  for (int i = 0; i < 16; ++i) {
    const int r = i * 4 + ty;
    tile[r][tx] = src[(size_t)(rbase + r) * DIM + tx];  // coalesced
  }
  __syncthreads();

  if (isS) {  // transposed copy (coalesced, pad-safe)
#pragma unroll
    for (int i = 0; i < 16; ++i) {
      const int d = i * 4 + ty;
      S_T[(size_t)d * NTOT + rbase + tx] = tile[tx][d];
    }
  }

  // Panel-swizzled f16; stores are lane-contiguous 16B.
  const int panel = tid >> 6;           // 0..3
  const int half = (tid >> 5) & 1;      // k-half
  const int slot0 = (tid & 31) * 2;     // slot = q8*16 + m
#pragma unroll
  for (int ss = 0; ss < 2; ++ss) {
    const int s = slot0 + ss;
    const int m = s & 15;
    const int q8 = s >> 4;
    const int row = panel * 16 + m;
    const int kb = half * 32 + q8 * 8;
    short8 hv;
#pragma unroll
    for (int j = 0; j < 8; ++j) hv[j] = (short)f16_bits(tile[row][kb + j]);
    const size_t goff =
        (size_t)((rbase >> 4) + panel) * 1024 + (size_t)half * 512 + (size_t)s * 8;
    *(short8*)&dh[goff] = hv;
  }

  // Row sum of squares (+ pre-scaled C-init for phaseA on the S side).
  if (tid < 64) {
    float acc = 0.0f;
#pragma unroll
    for (int d = 0; d < DIM; ++d) {
      const float v = tile[tid][d];
      acc = fmaf(v, v, acc);
    }
    if (isS) {
      sqS[rbase + tid] = acc;
      sqSc[rbase + tid] = CINIT_COEF * acc;  // same v_mul RNE as before
    } else {
      sqQ[rbase + tid] = acc;
    }
  }
}

// ---------------------------------------------------------------------------
// Phase A (R25 verbatim): block = 256 queries x 512 supports; 4 waves
// share the support panel via LDS (double-buffered 64-support chunks,
// global_load_lds width=16, linear dest, R8 lane-contiguous layout).
// grid = (32 splits, 64 q-tiles); split -> XCD via linear%8.
template <int BST>  // 16-support steps per bmin block: 8 -> SBLK=128
__global__ __launch_bounds__(256, 4) void k_phaseA(
    const ushort* __restrict__ Sh, const ushort* __restrict__ Qh,
    const float* __restrict__ sqSc, float* __restrict__ bmin) {
  constexpr int NSB = NTOT / (16 * BST);   // 128 or 64
  constexpr int SBLK = 16 * BST;
  __shared__ ushort spanel[2][4096];       // 2 x 8KB: 64 supports each
  __shared__ float ssq[2][64];

  const int tid = threadIdx.x;
  const int l = tid & 63;
  const int w = tid >> 6;
  const int lm = l & 15;
  const int lq = l >> 4;
  const int split = blockIdx.x;            // 0..31
  const int qbase = blockIdx.y * 256 + w * 64;
  const int sbase = split * 512;

  // Query (B) fragments: 4 tiles x 2 k-chunks, pinned (32 VGPR resident).
  short8 qh[4][2];
#pragma unroll
  for (int t = 0; t < 4; ++t) {
    const size_t pb = (size_t)((qbase >> 4) + t) * 1024 + (size_t)l * 8;
    qh[t][0] = *(const short8*)&Qh[pb];
    qh[t][1] = *(const short8*)&Qh[pb + 512];
  }
#pragma unroll
  for (int t = 0; t < 4; ++t) {
    pin8(qh[t][0]);
    pin8(qh[t][1]);
  }

  // Async stage of chunk c into buffer b; LDS dest is linear
  // (wave-uniform base + lane*16), panel layout is lane-contiguous.
  auto stage = [&](int c, int b) {
    const ushort* gs = Sh + ((size_t)(split * 32 + c * 4)) * 1024 +
                       (size_t)w * 1024 + (size_t)l * 8;
    ushort* ls = &spanel[b][w * 1024];
    __builtin_amdgcn_global_load_lds(
        (const __attribute__((address_space(1))) void*)(const void*)gs,
        (__attribute__((address_space(3))) void*)(void*)ls, 16, 0, 0);
    __builtin_amdgcn_global_load_lds(
        (const __attribute__((address_space(1))) void*)(const void*)(gs + 512),
        (__attribute__((address_space(3))) void*)(void*)(ls + 512), 16, 0, 0);
    if (tid < 16)
      *(float4*)&ssq[b][tid * 4] =
          *(const float4*)&sqSc[sbase + c * 64 + tid * 4];
  };

  float bmr[4] = {-FLT_BIG, -FLT_BIG, -FLT_BIG, -FLT_BIG};

  stage(0, 0);
  __syncthreads();  // implicit vmcnt(0) drain: chunk 0 resident

  for (int c = 0; c < 8; ++c) {
    const int b = c & 1;
    if (c + 1 < 8) stage(c + 1, b ^ 1);  // async issue before compute

#pragma unroll
    for (int st = 0; st < 4; ++st) {
      const short8 h0 = *(const short8*)&spanel[b][st * 1024 + l * 8];
      const short8 h1 = *(const short8*)&spanel[b][st * 1024 + 512 + l * 8];
      const float4 sqv = *(const float4*)&ssq[b][st * 16 + lq * 4];
      float4v cinit;
      cinit[0] = sqv.x;
      cinit[1] = sqv.y;
      cinit[2] = sqv.z;
      cinit[3] = sqv.w;
#pragma unroll
      for (int t = 0; t < 4; ++t) {
        float4v a = MFMA16F(h0, qh[t][0], cinit);
        a = MFMA16F(h1, qh[t][1], a);
        // v_max3(a0,a1,a2) + max(a3,bmr) + max. Exact (assoc/comm).
        bmr[t] = fmaxf(fmaxf(fmaxf(a[0], a[1]), a[2]), fmaxf(a[3], bmr[t]));
      }
    }

    if ((((c + 1) * 4) & (BST - 1)) == 0) {  // finished a bmin block
      const int gb = split * (512 / SBLK) + ((c + 1) * 64 / SBLK) - 1;
#pragma unroll
      for (int t = 0; t < 4; ++t) {
        float v = bmr[t];
        v = fmaxf(v, __shfl_xor(v, 16, 64));
        v = fmaxf(v, __shfl_xor(v, 32, 64));
        if (lq == 0) bmin[(size_t)(qbase + t * 16 + lm) * NSB + gb] = -2.0f * v;
        bmr[t] = -FLT_BIG;
      }
    }
    __syncthreads();  // drains stage(c+1) + guards buffer reuse
  }
}

// ---------------------------------------------------------------------------
// Phase B (R33): 128 threads = 2 waves, 2 queries per block, 8192 blocks.
// launch_bounds(128,2): VGPR cap 256 -> staging arrays CANNOT spill.
// Wave w owns query blockIdx*2+w; the 2 waves publish passing-block masks
// to LDS and round-robin the combined worklist (alternate items). R21
// register-staged rescore verbatim. Exact fp32 keys, d-ascending
// accumulation; strict-< ascending per lane + lexicographic merges =>
// np.argmin first-index.
template <int SBLK>
__global__ __launch_bounds__(128, 2) void k_phaseB(
    const float* __restrict__ S_T,   // [64][NTOT]
    const float* __restrict__ Q,     // [NTOT][64]
    const float* __restrict__ sqS, const float* __restrict__ sqQ,
    const float* __restrict__ bmin,
    const float* __restrict__ onehot, float* __restrict__ out) {
  constexpr int NSB = NTOT / SBLK;    // 128 or 64
  constexpr int NB64 = NSB / 64;
  constexpr int SPL = SBLK / 64;      // supports per lane: 2 or 4

  __shared__ float sQrow[2][64];
  __shared__ unsigned long long smask[2][NB64];
  __shared__ float sbk[2][2];
  __shared__ int sbi[2][2];

  const int lane = threadIdx.x & 63;
  const int w = threadIdx.x >> 6;     // 0..1
  const int q = blockIdx.x * 2 + w;

  if (lane < 16)
    *(float4*)&sQrow[w][lane * 4] = *(const float4*)&Q[(size_t)q * DIM + lane * 4];

  // Per-query certified filter width.
  const float eps = EPS_COEF * sqQ[q] + EPS_ABS;

  float bv[NB64];
#pragma unroll
  for (int j = 0; j < NB64; ++j) bv[j] = bmin[(size_t)q * NSB + j * 64 + lane];
  float m = bv[0];
#pragma unroll
  for (int j = 1; j < NB64; ++j) m = fminf(m, bv[j]);
#pragma unroll
  for (int d = 1; d < 64; d <<= 1) m = fminf(m, __shfl_xor(m, d, 64));
  const float thr = m + eps;

#pragma unroll
  for (int j = 0; j < NB64; ++j) {
    const unsigned long long msk = __ballot(bv[j] <= thr);
    if (lane == 0) smask[w][j] = msk;
  }
  __syncthreads();  // sQrow + smask visible block-wide

  // Round-robin the combined worklist (ascending block order per query
  // => per-lane ascending support index => strict-< keeps FIRST min).
  int idx = 0;
  for (int qq = 0; qq < 2; ++qq) {
    float bkq = FLT_BIG;
    int biq = 0;
    for (int j = 0; j < NB64; ++j) {
      unsigned long long msk = smask[qq][j];  // uniform broadcast read
      while (msk) {  // wave-uniform control
        const int b = j * 64 + (__ffsll((long long)msk) - 1);
        msk &= msk - 1;
        if ((idx++ & 1) != w) continue;
        const int s0 = b * SBLK + lane * SPL;
        if (SPL == 2) {
          // R21 register-staged rescore verbatim:
          // 2 halves x {32 float2 loads -> 64 fmaf}, d-ascending.
          float a0 = 0.f, a1 = 0.f;
#pragma unroll
          for (int h = 0; h < 2; ++h) {
            float2 x[32];
#pragma unroll
            for (int d = 0; d < 32; ++d)
              x[d] = *(const float2*)&S_T[(size_t)(h * 32 + d) * NTOT + s0];
#pragma unroll
            for (int d = 0; d < 32; ++d) {
              const float qd = sQrow[qq][h * 32 + d];
              a0 = fmaf(qd, x[d].x, a0);
              a1 = fmaf(qd, x[d].y, a1);
            }
          }
          const float2 sq2 = *(const float2*)&sqS[s0];
          const float k0 = fmaf(-2.f, a0, sq2.x);
          const float k1 = fmaf(-2.f, a1, sq2.y);
          bool u;  // ascending index, strict < => first minimum per lane
          u = k0 < bkq; bkq = u ? k0 : bkq; biq = u ? s0 : biq;
          u = k1 < bkq; bkq = u ? k1 : bkq; biq = u ? (s0 + 1) : biq;
        } else {
          // R21 SPL==4 path verbatim (fallback config).
          float a0 = 0.f, a1 = 0.f, a2 = 0.f, a3 = 0.f;
#pragma unroll
          for (int hh = 0; hh < 4; ++hh) {
            float4 x4[16];
#pragma unroll
            for (int d = 0; d < 16; ++d)
              x4[d] = *(const float4*)&S_T[(size_t)(hh * 16 + d) * NTOT + s0];
#pragma unroll
            for (int d = 0; d < 16; ++d) {
              const float qd = sQrow[qq][hh * 16 + d];
              a0 = fmaf(qd, x4[d].x, a0);
              a1 = fmaf(qd, x4[d].y, a1);
              a2 = fmaf(qd, x4[d].z, a2);
              a3 = fmaf(qd, x4[d].w, a3);
            }
          }
          const float4 sq4 = *(const float4*)&sqS[s0];
          const float k0 = fmaf(-2.f, a0, sq4.x);
          const float k1 = fmaf(-2.f, a1, sq4.y);
          const float k2 = fmaf(-2.f, a2, sq4.z);
          const float k3 = fmaf(-2.f, a3, sq4.w);
          bool u;
          u = k0 < bkq; bkq = u ? k0 : bkq; biq = u ? s0 : biq;
          u = k1 < bkq; bkq = u ? k1 : bkq; biq = u ? (s0 + 1) : biq;
          u = k2 < bkq; bkq = u ? k2 : bkq; biq = u ? (s0 + 2) : biq;
          u = k3 < bkq; bkq = u ? k3 : bkq; biq = u ? (s0 + 3) : biq;
        }
      }
    }
    // Cross-lane lexicographic argmin on exact keys => first-index.
#pragma unroll
    for (int d = 1; d < 64; d <<= 1) {
      const float ok = __shfl_xor(bkq, d, 64);
      const int oi = __shfl_xor(biq, d, 64);
      const bool u = (ok < bkq) || (ok == bkq && oi < biq);
      bkq = u ? ok : bkq;
      biq = u ? oi : biq;
    }
    if (lane == 0) { sbk[qq][w] = bkq; sbi[qq][w] = biq; }
  }
  __syncthreads();

  // Wave w: lexicographic merge of the 2 wave partials for query w.
  // (Disjoint item subsets; ties resolved by smaller index => first-index.)
  float fk = sbk[w][0];
  int fi = sbi[w][0];
  {
    const float ok = sbk[w][1];
    const int oi = sbi[w][1];
    const bool u = (ok < fk) || (ok == fk && oi < fi);
    fk = u ? ok : fk;
    fi = u ? oi : fi;
  }

  // Label: one-hot rows exact {0,1}; first 1 == np.argmax.
  const float ov = onehot[(size_t)fi * 64 + lane];
  const unsigned long long lmask = __ballot(ov > 0.5f);
  const int label = __ffsll((long long)lmask) - 1;
  out[(size_t)q * 64 + lane] = (lane == label) ? 1.0f : 0.0f;
}

// ---------------------------------------------------------------------------
extern "C" void kernel_launch(void* const* d_in, const int* in_sizes, int n_in,
                              void* d_out, int out_size, void* d_ws, size_t ws_size,
                              hipStream_t stream) {
  const float* S = (const float*)d_in[0];   // [16384][64]
  const float* Q = (const float*)d_in[1];   // [16384][64]
  const float* OH = (const float*)d_in[2];  // [16384][64]
  float* out = (float*)d_out;

  char* ws = (char*)d_ws;
  ushort* Sh = (ushort*)ws;                                  // [0, 2MB)
  ushort* Qh = (ushort*)(ws + (2u << 20));                   // [2, 4MB)
  float* S_T = (float*)(ws + (4u << 20));                    // [4, 8MB)
  float* sqS = (float*)(ws + (8u << 20));                    // 64 KB
  float* sqQ = (float*)(ws + (8u << 20) + (64u << 10));      // 64 KB
  float* sqSc = (float*)(ws + (8u << 20) + (128u << 10));    // 64 KB
  float* bmin = (float*)(ws + (8u << 20) + (192u << 10));    // up to 8 MB

  k_prep<<<dim3(512), 256, 0, stream>>>(S, Q, Sh, Qh, sqS, sqQ, sqSc, S_T);

  // 128-granular bmin (8 MB) if workspace allows; else 256-granular (4 MB).
  if (ws_size >= (17u << 20)) {
    k_phaseA<8><<<dim3(32, NTOT / 256), 256, 0, stream>>>(Sh, Qh, sqSc, bmin);
    k_phaseB<128><<<dim3(NTOT / 2), 128, 0, stream>>>(S_T, Q, sqS, sqQ,
                                                      bmin, OH, out);
  } else {
    k_phaseA<16><<<dim3(32, NTOT / 256), 256, 0, stream>>>(Sh, Qh, sqSc, bmin);
    k_phaseB<256><<<dim3(NTOT / 2), 128, 0, stream>>>(S_T, Q, sqS, sqQ,
                                                      bmin, OH, out);
  }
  (void)in_sizes; (void)n_in; (void)out_size; (void)ws_size;
}

// Round 15
// 144.592 us; speedup vs baseline: 2.1507x; 1.0075x over previous
//
#include <hip/hip_runtime.h>

// KNN argmin over L2, round 34: R33 build + tightened certificate
// constant c: 2^-9*1.01 (0.00197) -> 2^-10*1.05 (0.001025).
//
// R33 post-mortem: spill fixed (VGPR 84, WRITE 4MB) but phaseB = 47.5us
// == R21's 48.7 despite halved chain + doubled WGs: rounds-x-chain dead.
// Unified L2-BW theory (fits ALL phaseB invariances): VALUBusy 24% ->
// ~55-60K rescore items (~3.5 blocks/query pass; eps~0.31 is wide) x
// 32KB S_T reads = ~1.8GB L2 in 48us ~= 37 TB/s ~= the 34.5 TB/s L2
// ceiling. phaseB is L2-bound; occupancy/chain/staging don't change
// bytes; SBLK halving was flat because bytes/item x items is constant.
//
// R34 lever: halve the filter width. Tight f16-product error bound:
// (2*2^-11 + 2^-22)|s||q| + 64*2^-24|s||q| <= 0.000981|s||q|. The old
// c=0.002 carried a 2x margin whose purpose (subnormal flush ~0.02,
// fp32 accum ~4e-4) is already covered by EPS_ABS=0.05. New c =
// 2^-10*1.05 = 0.001025 > 0.000981 (4.5% margin):
//   CINIT_COEF = -(1-c)/2 = -0.4994875, EPS_COEF = 2c = 0.00205.
// eps: 0.31 -> 0.18 => passing blocks ~x0.6 => L2 bytes ~x0.6.
//
// Falsifiers: absmax != 0 => margin was load-bearing, revert constants.
// phaseB flat => item count not the pacer => declare plateau.
//
// Everything else identical to R33 (prep/phaseA = R25-proven bodies;
// phaseB = 2-wave/8192-WG work steal, launch_bounds(128,2), R21 staging).
//
// Ledger: R19 153.3 | R20 153.0 | R21 145.8 | R22 no-op | R23 314.8
// spills | R24 153.1 | R25 145.8 | R26 221.7 | R27 203.9 | R28 160.7 |
// R29 166.1 | R30 197.7 spills | R31 168.3 | R32 311.0 spills |
// R33 145.7 BEST (spill fixed; rounds-x-chain falsified).
// Prediction: phaseB 30-38us; total ~128-137.

#define NTOT   16384
#define DIM    64
#define EPS_COEF 0.00205f       // 2c with c = 2^-10*1.05 = 0.001025
#define EPS_ABS  0.05f          // unchanged: covers flush + fp32 accum
#define CINIT_COEF (-0.4994875f)  // -(1-c)/2
#define FLT_BIG 3.4e38f

typedef __attribute__((ext_vector_type(8))) short short8;
typedef __attribute__((ext_vector_type(4))) float float4v;

__device__ __forceinline__ ushort f16_bits(float x) {
  union { _Float16 f; ushort u; } c;
  c.f = (_Float16)x;  // v_cvt_f16_f32, RNE
  return c.u;
}

// Opaque def: forbids rematerialization (forces register residency).
__device__ __forceinline__ void pin8(short8& v) {
  asm volatile("" : "+v"(v));
}

#define MFMA16F(A, B, C) __builtin_amdgcn_mfma_f32_16x16x32_f16(A, B, C, 0, 0, 0)

// ---------------------------------------------------------------------------
// Fused prep (R22/R25 verbatim): blocks 0..255 -> S (f16 panels + sqS +
// sqSc + S_T); 256..511 -> Q (panels + sqQ). Panel layout (R8-proven):
//   off(r,k) = (r>>4)*1024 + (k>>5)*512 + (((k&31)>>3)*16 + (r&15))*8 + (k&7)
__global__ __launch_bounds__(256) void k_prep(
    const float* __restrict__ S, const float* __restrict__ Q,
    ushort* __restrict__ Sh, ushort* __restrict__ Qh,
    float* __restrict__ sqS, float* __restrict__ sqQ,
    float* __restrict__ sqSc, float* __restrict__ S_T) {
  __shared__ float tile[64][65];
  const int tid = threadIdx.x;
  const bool isS = blockIdx.x < 256;
  const int rbase = (blockIdx.x & 255) * 64;
  const float* __restrict__ src = isS ? S : Q;
  ushort* __restrict__ dh = isS ? Sh : Qh;

  const int tx = tid & 63;
  const int ty = tid >> 6;
#pragma unroll
  for (int i = 0; i < 16; ++i) {
    const int r = i * 4 + ty;
    tile[r][tx] = src[(size_t)(rbase + r) * DIM + tx];  // coalesced
  }
  __syncthreads();

  if (isS) {  // transposed copy (coalesced, pad-safe)
#pragma unroll
    for (int i = 0; i < 16; ++i) {
      const int d = i * 4 + ty;
      S_T[(size_t)d * NTOT + rbase + tx] = tile[tx][d];
    }
  }

  // Panel-swizzled f16; stores are lane-contiguous 16B.
  const int panel = tid >> 6;           // 0..3
  const int half = (tid >> 5) & 1;      // k-half
  const int slot0 = (tid & 31) * 2;     // slot = q8*16 + m
#pragma unroll
  for (int ss = 0; ss < 2; ++ss) {
    const int s = slot0 + ss;
    const int m = s & 15;
    const int q8 = s >> 4;
    const int row = panel * 16 + m;
    const int kb = half * 32 + q8 * 8;
    short8 hv;
#pragma unroll
    for (int j = 0; j < 8; ++j) hv[j] = (short)f16_bits(tile[row][kb + j]);
    const size_t goff =
        (size_t)((rbase >> 4) + panel) * 1024 + (size_t)half * 512 + (size_t)s * 8;
    *(short8*)&dh[goff] = hv;
  }

  // Row sum of squares (+ pre-scaled C-init for phaseA on the S side).
  if (tid < 64) {
    float acc = 0.0f;
#pragma unroll
    for (int d = 0; d < DIM; ++d) {
      const float v = tile[tid][d];
      acc = fmaf(v, v, acc);
    }
    if (isS) {
      sqS[rbase + tid] = acc;
      sqSc[rbase + tid] = CINIT_COEF * acc;  // same v_mul RNE, new coef
    } else {
      sqQ[rbase + tid] = acc;
    }
  }
}

// ---------------------------------------------------------------------------
// Phase A (R25 verbatim): block = 256 queries x 512 supports; 4 waves
// share the support panel via LDS (double-buffered 64-support chunks,
// global_load_lds width=16, linear dest, R8 lane-contiguous layout).
// grid = (32 splits, 64 q-tiles); split -> XCD via linear%8.
template <int BST>  // 16-support steps per bmin block: 8 -> SBLK=128
__global__ __launch_bounds__(256, 4) void k_phaseA(
    const ushort* __restrict__ Sh, const ushort* __restrict__ Qh,
    const float* __restrict__ sqSc, float* __restrict__ bmin) {
  constexpr int NSB = NTOT / (16 * BST);   // 128 or 64
  constexpr int SBLK = 16 * BST;
  __shared__ ushort spanel[2][4096];       // 2 x 8KB: 64 supports each
  __shared__ float ssq[2][64];

  const int tid = threadIdx.x;
  const int l = tid & 63;
  const int w = tid >> 6;
  const int lm = l & 15;
  const int lq = l >> 4;
  const int split = blockIdx.x;            // 0..31
  const int qbase = blockIdx.y * 256 + w * 64;
  const int sbase = split * 512;

  // Query (B) fragments: 4 tiles x 2 k-chunks, pinned (32 VGPR resident).
  short8 qh[4][2];
#pragma unroll
  for (int t = 0; t < 4; ++t) {
    const size_t pb = (size_t)((qbase >> 4) + t) * 1024 + (size_t)l * 8;
    qh[t][0] = *(const short8*)&Qh[pb];
    qh[t][1] = *(const short8*)&Qh[pb + 512];
  }
#pragma unroll
  for (int t = 0; t < 4; ++t) {
    pin8(qh[t][0]);
    pin8(qh[t][1]);
  }

  // Async stage of chunk c into buffer b; LDS dest is linear
  // (wave-uniform base + lane*16), panel layout is lane-contiguous.
  auto stage = [&](int c, int b) {
    const ushort* gs = Sh + ((size_t)(split * 32 + c * 4)) * 1024 +
                       (size_t)w * 1024 + (size_t)l * 8;
    ushort* ls = &spanel[b][w * 1024];
    __builtin_amdgcn_global_load_lds(
        (const __attribute__((address_space(1))) void*)(const void*)gs,
        (__attribute__((address_space(3))) void*)(void*)ls, 16, 0, 0);
    __builtin_amdgcn_global_load_lds(
        (const __attribute__((address_space(1))) void*)(const void*)(gs + 512),
        (__attribute__((address_space(3))) void*)(void*)(ls + 512), 16, 0, 0);
    if (tid < 16)
      *(float4*)&ssq[b][tid * 4] =
          *(const float4*)&sqSc[sbase + c * 64 + tid * 4];
  };

  float bmr[4] = {-FLT_BIG, -FLT_BIG, -FLT_BIG, -FLT_BIG};

  stage(0, 0);
  __syncthreads();  // implicit vmcnt(0) drain: chunk 0 resident

  for (int c = 0; c < 8; ++c) {
    const int b = c & 1;
    if (c + 1 < 8) stage(c + 1, b ^ 1);  // async issue before compute

#pragma unroll
    for (int st = 0; st < 4; ++st) {
      const short8 h0 = *(const short8*)&spanel[b][st * 1024 + l * 8];
      const short8 h1 = *(const short8*)&spanel[b][st * 1024 + 512 + l * 8];
      const float4 sqv = *(const float4*)&ssq[b][st * 16 + lq * 4];
      float4v cinit;
      cinit[0] = sqv.x;
      cinit[1] = sqv.y;
      cinit[2] = sqv.z;
      cinit[3] = sqv.w;
#pragma unroll
      for (int t = 0; t < 4; ++t) {
        float4v a = MFMA16F(h0, qh[t][0], cinit);
        a = MFMA16F(h1, qh[t][1], a);
        // v_max3(a0,a1,a2) + max(a3,bmr) + max. Exact (assoc/comm).
        bmr[t] = fmaxf(fmaxf(fmaxf(a[0], a[1]), a[2]), fmaxf(a[3], bmr[t]));
      }
    }

    if ((((c + 1) * 4) & (BST - 1)) == 0) {  // finished a bmin block
      const int gb = split * (512 / SBLK) + ((c + 1) * 64 / SBLK) - 1;
#pragma unroll
      for (int t = 0; t < 4; ++t) {
        float v = bmr[t];
        v = fmaxf(v, __shfl_xor(v, 16, 64));
        v = fmaxf(v, __shfl_xor(v, 32, 64));
        if (lq == 0) bmin[(size_t)(qbase + t * 16 + lm) * NSB + gb] = -2.0f * v;
        bmr[t] = -FLT_BIG;
      }
    }
    __syncthreads();  // drains stage(c+1) + guards buffer reuse
  }
}

// ---------------------------------------------------------------------------
// Phase B (R33 verbatim): 128 threads = 2 waves, 2 queries per block,
// 8192 blocks, launch_bounds(128,2) (VGPR cap 256 -> no spill). Waves
// publish passing-block masks to LDS and round-robin the combined
// worklist. R21 register-staged rescore verbatim. Exact fp32 keys,
// d-ascending accumulation; strict-< ascending per lane + lexicographic
// merges => np.argmin first-index.
template <int SBLK>
__global__ __launch_bounds__(128, 2) void k_phaseB(
    const float* __restrict__ S_T,   // [64][NTOT]
    const float* __restrict__ Q,     // [NTOT][64]
    const float* __restrict__ sqS, const float* __restrict__ sqQ,
    const float* __restrict__ bmin,
    const float* __restrict__ onehot, float* __restrict__ out) {
  constexpr int NSB = NTOT / SBLK;    // 128 or 64
  constexpr int NB64 = NSB / 64;
  constexpr int SPL = SBLK / 64;      // supports per lane: 2 or 4

  __shared__ float sQrow[2][64];
  __shared__ unsigned long long smask[2][NB64];
  __shared__ float sbk[2][2];
  __shared__ int sbi[2][2];

  const int lane = threadIdx.x & 63;
  const int w = threadIdx.x >> 6;     // 0..1
  const int q = blockIdx.x * 2 + w;

  if (lane < 16)
    *(float4*)&sQrow[w][lane * 4] = *(const float4*)&Q[(size_t)q * DIM + lane * 4];

  // Per-query certified filter width.
  const float eps = EPS_COEF * sqQ[q] + EPS_ABS;

  float bv[NB64];
#pragma unroll
  for (int j = 0; j < NB64; ++j) bv[j] = bmin[(size_t)q * NSB + j * 64 + lane];
  float m = bv[0];
#pragma unroll
  for (int j = 1; j < NB64; ++j) m = fminf(m, bv[j]);
#pragma unroll
  for (int d = 1; d < 64; d <<= 1) m = fminf(m, __shfl_xor(m, d, 64));
  const float thr = m + eps;

#pragma unroll
  for (int j = 0; j < NB64; ++j) {
    const unsigned long long msk = __ballot(bv[j] <= thr);
    if (lane == 0) smask[w][j] = msk;
  }
  __syncthreads();  // sQrow + smask visible block-wide

  // Round-robin the combined worklist (ascending block order per query
  // => per-lane ascending support index => strict-< keeps FIRST min).
  int idx = 0;
  for (int qq = 0; qq < 2; ++qq) {
    float bkq = FLT_BIG;
    int biq = 0;
    for (int j = 0; j < NB64; ++j) {
      unsigned long long msk = smask[qq][j];  // uniform broadcast read
      while (msk) {  // wave-uniform control
        const int b = j * 64 + (__ffsll((long long)msk) - 1);
        msk &= msk - 1;
        if ((idx++ & 1) != w) continue;
        const int s0 = b * SBLK + lane * SPL;
        if (SPL == 2) {
          // R21 register-staged rescore verbatim:
          // 2 halves x {32 float2 loads -> 64 fmaf}, d-ascending.
          float a0 = 0.f, a1 = 0.f;
#pragma unroll
          for (int h = 0; h < 2; ++h) {
            float2 x[32];
#pragma unroll
            for (int d = 0; d < 32; ++d)
              x[d] = *(const float2*)&S_T[(size_t)(h * 32 + d) * NTOT + s0];
#pragma unroll
            for (int d = 0; d < 32; ++d) {
              const float qd = sQrow[qq][h * 32 + d];
              a0 = fmaf(qd, x[d].x, a0);
              a1 = fmaf(qd, x[d].y, a1);
            }
          }
          const float2 sq2 = *(const float2*)&sqS[s0];
          const float k0 = fmaf(-2.f, a0, sq2.x);
          const float k1 = fmaf(-2.f, a1, sq2.y);
          bool u;  // ascending index, strict < => first minimum per lane
          u = k0 < bkq; bkq = u ? k0 : bkq; biq = u ? s0 : biq;
          u = k1 < bkq; bkq = u ? k1 : bkq; biq = u ? (s0 + 1) : biq;
        } else {
          // R21 SPL==4 path verbatim (fallback config).
          float a0 = 0.f, a1 = 0.f, a2 = 0.f, a3 = 0.f;
#pragma unroll
          for (int hh = 0; hh < 4; ++hh) {
            float4 x4[16];
#pragma unroll
            for (int d = 0; d < 16; ++d)
              x4[d] = *(const float4*)&S_T[(size_t)(hh * 16 + d) * NTOT + s0];
#pragma unroll
            for (int d = 0; d < 16; ++d) {
              const float qd = sQrow[qq][hh * 16 + d];
              a0 = fmaf(qd, x4[d].x, a0);
              a1 = fmaf(qd, x4[d].y, a1);
              a2 = fmaf(qd, x4[d].z, a2);
              a3 = fmaf(qd, x4[d].w, a3);
            }
          }
          const float4 sq4 = *(const float4*)&sqS[s0];
          const float k0 = fmaf(-2.f, a0, sq4.x);
          const float k1 = fmaf(-2.f, a1, sq4.y);
          const float k2 = fmaf(-2.f, a2, sq4.z);
          const float k3 = fmaf(-2.f, a3, sq4.w);
          bool u;
          u = k0 < bkq; bkq = u ? k0 : bkq; biq = u ? s0 : biq;
          u = k1 < bkq; bkq = u ? k1 : bkq; biq = u ? (s0 + 1) : biq;
          u = k2 < bkq; bkq = u ? k2 : bkq; biq = u ? (s0 + 2) : biq;
          u = k3 < bkq; bkq = u ? k3 : bkq; biq = u ? (s0 + 3) : biq;
        }
      }
    }
    // Cross-lane lexicographic argmin on exact keys => first-index.
#pragma unroll
    for (int d = 1; d < 64; d <<= 1) {
      const float ok = __shfl_xor(bkq, d, 64);
      const int oi = __shfl_xor(biq, d, 64);
      const bool u = (ok < bkq) || (ok == bkq && oi < biq);
      bkq = u ? ok : bkq;
      biq = u ? oi : biq;
    }
    if (lane == 0) { sbk[qq][w] = bkq; sbi[qq][w] = biq; }
  }
  __syncthreads();

  // Wave w: lexicographic merge of the 2 wave partials for query w.
  // (Disjoint item subsets; ties resolved by smaller index => first-index.)
  float fk = sbk[w][0];
  int fi = sbi[w][0];
  {
    const float ok = sbk[w][1];
    const int oi = sbi[w][1];
    const bool u = (ok < fk) || (ok == fk && oi < fi);
    fk = u ? ok : fk;
    fi = u ? oi : fi;
  }

  // Label: one-hot rows exact {0,1}; first 1 == np.argmax.
  const float ov = onehot[(size_t)fi * 64 + lane];
  const unsigned long long lmask = __ballot(ov > 0.5f);
  const int label = __ffsll((long long)lmask) - 1;
  out[(size_t)q * 64 + lane] = (lane == label) ? 1.0f : 0.0f;
}

// ---------------------------------------------------------------------------
extern "C" void kernel_launch(void* const* d_in, const int* in_sizes, int n_in,
                              void* d_out, int out_size, void* d_ws, size_t ws_size,
                              hipStream_t stream) {
  const float* S = (const float*)d_in[0];   // [16384][64]
  const float* Q = (const float*)d_in[1];   // [16384][64]
  const float* OH = (const float*)d_in[2];  // [16384][64]
  float* out = (float*)d_out;

  char* ws = (char*)d_ws;
  ushort* Sh = (ushort*)ws;                                  // [0, 2MB)
  ushort* Qh = (ushort*)(ws + (2u << 20));                   // [2, 4MB)
  float* S_T = (float*)(ws + (4u << 20));                    // [4, 8MB)
  float* sqS = (float*)(ws + (8u << 20));                    // 64 KB
  float* sqQ = (float*)(ws + (8u << 20) + (64u << 10));      // 64 KB
  float* sqSc = (float*)(ws + (8u << 20) + (128u << 10));    // 64 KB
  float* bmin = (float*)(ws + (8u << 20) + (192u << 10));    // up to 8 MB

  k_prep<<<dim3(512), 256, 0, stream>>>(S, Q, Sh, Qh, sqS, sqQ, sqSc, S_T);

  // 128-granular bmin (8 MB) if workspace allows; else 256-granular (4 MB).
  if (ws_size >= (17u << 20)) {
    k_phaseA<8><<<dim3(32, NTOT / 256), 256, 0, stream>>>(Sh, Qh, sqSc, bmin);
    k_phaseB<128><<<dim3(NTOT / 2), 128, 0, stream>>>(S_T, Q, sqS, sqQ,
                                                      bmin, OH, out);
  } else {
    k_phaseA<16><<<dim3(32, NTOT / 256), 256, 0, stream>>>(Sh, Qh, sqSc, bmin);
    k_phaseB<256><<<dim3(NTOT / 2), 128, 0, stream>>>(S_T, Q, sqS, sqQ,
                                                      bmin, OH, out);
  }
  (void)in_sizes; (void)n_in; (void)out_size; (void)ws_size;
}